// Round 1
// baseline (984.356 us; speedup 1.0000x reference)
//
#include <hip/hip_runtime.h>
#include <math.h>

// Routing-by-agreement, fused formulation.
// b_batch is never materialized: logits are recomputed per row from stored
// s-buffers (squash applied on the fly), so each iteration is ONE pass over u.
// 4 passes total over the 512 MiB u tensor -> ~2.15 GB HBM read (roofline ~340us).

namespace {
constexpr int BATCH = 128;
constexpr int IC    = 2048;
constexpr int OC    = 32;
constexpr int OD    = 16;
constexpr int ROW   = OC * OD;              // 512 floats per (b,i) row
constexpr int BPB   = 16;                   // blocks per batch
constexpr int ROWS_PER_BLOCK = IC / BPB;    // 128
constexpr int NWAVES = 4;                   // 256 threads / 64
} // namespace

__device__ __forceinline__ float dot8(const float4& a0, const float4& a1,
                                      const float4& b0, const float4& b1) {
    return a0.x*b0.x + a0.y*b0.y + a0.z*b0.z + a0.w*b0.w
         + a1.x*b1.x + a1.y*b1.y + a1.z*b1.z + a1.w*b1.w;
}

// One routing pass. NV = number of previous v's folded into the logits.
// sbuf holds the s accumulators of previous passes (v = squash(s) computed
// in-register here). s_out is atomically accumulated (must be pre-zeroed).
template<int NV>
__global__ void __launch_bounds__(256)
routing_pass(const float* __restrict__ u,
             const float* __restrict__ blogit,
             const float* __restrict__ sbuf,
             float* __restrict__ s_out)
{
    const int tid   = threadIdx.x;
    const int lane  = tid & 63;
    const int wave  = tid >> 6;
    const int b     = blockIdx.x / BPB;
    const int chunk = blockIdx.x % BPB;
    const int i0    = chunk * ROWS_PER_BLOCK;

    const int o     = lane >> 1;      // lane pair (2k,2k+1) owns output-cap o=k
    const int elem0 = lane * 8;       // this lane's 8 floats within the 512-float row

    // Preload v fragments: v_t = squash(s_t), computed from the s buffers.
    float4 v0[NV > 0 ? NV : 1];
    float4 v1[NV > 0 ? NV : 1];
#pragma unroll
    for (int t = 0; t < NV; ++t) {
        const float* sp = sbuf + ((size_t)t * BATCH + b) * ROW + elem0;
        float4 x0 = *(const float4*)sp;
        float4 x1 = *(const float4*)(sp + 4);
        float part = x0.x*x0.x + x0.y*x0.y + x0.z*x0.z + x0.w*x0.w
                   + x1.x*x1.x + x1.y*x1.y + x1.z*x1.z + x1.w*x1.w;
        float sq = part + __shfl_xor(part, 1, 64);          // sum over all 16 d
        float scale = sqrtf(sq) / (1.0f + sq);              // == sq/(1+sq)/sqrt(sq)
        x0.x *= scale; x0.y *= scale; x0.z *= scale; x0.w *= scale;
        x1.x *= scale; x1.y *= scale; x1.z *= scale; x1.w *= scale;
        v0[t] = x0; v1[t] = x1;
    }

    float4 acc0 = make_float4(0.f, 0.f, 0.f, 0.f);
    float4 acc1 = make_float4(0.f, 0.f, 0.f, 0.f);

    for (int i = i0 + wave; i < i0 + ROWS_PER_BLOCK; i += NWAVES) {
        const float* urow = u + ((size_t)b * IC + i) * ROW + elem0;
        float4 u0 = *(const float4*)urow;
        float4 u1 = *(const float4*)(urow + 4);

        // logits: b[i,o] + sum_t <u_row_o, v_t_o>
        float bb = blogit[i * OC + o];
#pragma unroll
        for (int t = 0; t < NV; ++t) {
            float part = dot8(u0, u1, v0[t], v1[t]);
            bb += part + __shfl_xor(part, 1, 64);           // full dot over d
        }

        // softmax over the 32 distinct o's. Values are duplicated across lane
        // pairs; xor-offsets {2,4,8,16,32} reduce over one representative of
        // each pair -> exact max/sum over o, no duplicate correction needed.
        float m = bb;
#pragma unroll
        for (int off = 2; off <= 32; off <<= 1)
            m = fmaxf(m, __shfl_xor(m, off, 64));
        float e = __expf(bb - m);
        float ssum = e;
#pragma unroll
        for (int off = 2; off <= 32; off <<= 1)
            ssum += __shfl_xor(ssum, off, 64);
        const float c = e / ssum;

        acc0.x += c * u0.x; acc0.y += c * u0.y; acc0.z += c * u0.z; acc0.w += c * u0.w;
        acc1.x += c * u1.x; acc1.y += c * u1.y; acc1.z += c * u1.z; acc1.w += c * u1.w;
    }

    // Block-level reduction of the per-wave partial s, then one atomicAdd per
    // element per block (16 blocks/batch contend per address -> trivial).
    __shared__ float red[NWAVES * ROW];                     // 8 KiB
    float* my = red + wave * ROW + elem0;
    *(float4*)my       = acc0;
    *(float4*)(my + 4) = acc1;
    __syncthreads();

    float* dst = s_out + (size_t)b * ROW;
    for (int p = tid; p < ROW; p += 256) {
        float val = red[p] + red[ROW + p] + red[2 * ROW + p] + red[3 * ROW + p];
        atomicAdd(dst + p, val);
    }
}

// Final squash: v = s * sqrt(|s|^2) / (1 + |s|^2), reduced over d (16 contiguous).
__global__ void __launch_bounds__(256)
squash_out(const float* __restrict__ s, float* __restrict__ out)
{
    const int idx = blockIdx.x * 256 + threadIdx.x;
    const float x = s[idx];
    float p = x * x;
    p += __shfl_xor(p, 1, 64);
    p += __shfl_xor(p, 2, 64);
    p += __shfl_xor(p, 4, 64);
    p += __shfl_xor(p, 8, 64);
    const float scale = sqrtf(p) / (1.0f + p);
    out[idx] = x * scale;
}

extern "C" void kernel_launch(void* const* d_in, const int* in_sizes, int n_in,
                              void* d_out, int out_size, void* d_ws, size_t ws_size,
                              hipStream_t stream)
{
    const float* u  = (const float*)d_in[0];   // [128, 2048, 32, 16] fp32
    const float* bl = (const float*)d_in[1];   // [2048, 32] fp32
    float* out  = (float*)d_out;               // [128, 32, 16] fp32
    float* sbuf = (float*)d_ws;                // 4 x [128,512] fp32 = 1 MiB scratch

    constexpr size_t SSZ = (size_t)BATCH * ROW;

    // s buffers are atomically accumulated -> zero them (ws is poisoned 0xAA).
    hipMemsetAsync(sbuf, 0, 4 * SSZ * sizeof(float), stream);

    dim3 grid(BATCH * BPB), block(256);
    // pass 0: c = softmax(b) -> s0
    routing_pass<0><<<grid, block, 0, stream>>>(u, bl, sbuf, sbuf + 0 * SSZ);
    // iter 1: logits = b + u.v0          -> s1
    routing_pass<1><<<grid, block, 0, stream>>>(u, bl, sbuf, sbuf + 1 * SSZ);
    // iter 2: logits = b + u.v0 + u.v1   -> s2
    routing_pass<2><<<grid, block, 0, stream>>>(u, bl, sbuf, sbuf + 2 * SSZ);
    // iter 3: logits = b + u.v0 + u.v1 + u.v2 -> s3
    routing_pass<3><<<grid, block, 0, stream>>>(u, bl, sbuf, sbuf + 3 * SSZ);
    // v3 = squash(s3) -> output
    squash_out<<<dim3((BATCH * ROW) / 256), block, 0, stream>>>(sbuf + 3 * SSZ, out);
}

// Round 3
// 856.589 us; speedup vs baseline: 1.1492x; 1.1492x over previous
//
#include <hip/hip_runtime.h>
#include <math.h>

// Routing-by-agreement, fused formulation v2.1 (fix: nontemporal builtins need
// native clang vector types, not HIP_vector_type float4).
//
// Key algebra: logits at iter k = b + u·(v0+...+v_{k-1}) = b + u·w  (linear!)
// so each pass needs ONE dot against a precomputed running sum w, regardless
// of iteration index. w is maintained by the tiny reduce kernel.
//
// Traffic plan: pass0 reads fp32 u (537 MB) once, emits fp16 copy (268 MB);
// passes 1-3 read fp16 (268 MB each). Total ~1.36 GB read + 0.29 GB write.
// No atomics: blocks write 2 KB partials, reduce kernel sums 16 per batch.

namespace {
constexpr int BATCH = 128;
constexpr int IC    = 2048;
constexpr int OC    = 32;
constexpr int OD    = 16;
constexpr int ROW   = OC * OD;            // 512 floats per (b,i) row
constexpr int BPB   = 16;                 // blocks per batch
constexpr int ROWS_PER_BLOCK = IC / BPB;  // 128
constexpr int NWAVES = 4;                 // 256 threads

typedef _Float16 half8 __attribute__((ext_vector_type(8)));
typedef float    f32x4 __attribute__((ext_vector_type(4)));

// workspace carve (bytes)
constexpr size_t OFF_U16  = 0;                         // 268435456 B
constexpr size_t OFF_PART = 268435456;                 // 2048*512*4 = 4 MiB
constexpr size_t OFF_W    = OFF_PART + 4194304;        // 128*512*4 = 256 KiB
constexpr size_t OFF_C0   = OFF_W + 262144;            // 2048*32*4 = 256 KiB
} // namespace

// c0[i,o] = softmax over o of blogit[i,:]
__global__ void __launch_bounds__(256)
softmax_b(const float* __restrict__ blogit, float* __restrict__ c0)
{
    const int idx = blockIdx.x * 256 + threadIdx.x;   // over IC*OC, 32-aligned groups
    float x = blogit[idx];
    float m = x;
#pragma unroll
    for (int off = 1; off <= 16; off <<= 1)
        m = fmaxf(m, __shfl_xor(m, off, 64));
    float e = __expf(x - m);
    float s = e;
#pragma unroll
    for (int off = 1; off <= 16; off <<= 1)
        s += __shfl_xor(s, off, 64);
    c0[idx] = e / s;
}

// pass 0: s0_partial = sum_i c0[i,o]*u  AND write fp16 copy of u.
__global__ void __launch_bounds__(256)
pass0_convert(const float* __restrict__ u, const float* __restrict__ c0,
              _Float16* __restrict__ u16, float* __restrict__ partials)
{
    const int tid = threadIdx.x, lane = tid & 63, wave = tid >> 6;
    const int b = blockIdx.x >> 4, chunk = blockIdx.x & 15;
    const int o = lane >> 1, elem0 = lane * 8;
    const int i_base = chunk * ROWS_PER_BLOCK + wave * 32;

    f32x4 acc0 = {0.f,0.f,0.f,0.f}, acc1 = {0.f,0.f,0.f,0.f};

    const float*  ubase = u   + ((size_t)b * IC + i_base) * ROW + elem0;
    _Float16*     obase = u16 + ((size_t)b * IC + i_base) * ROW + elem0;

#pragma unroll 4
    for (int r = 0; r < 32; ++r) {
        const float* up = ubase + (size_t)r * ROW;
        f32x4 u0 = __builtin_nontemporal_load((const f32x4*)up);
        f32x4 u1 = __builtin_nontemporal_load((const f32x4*)(up + 4));
        float c = c0[(i_base + r) * OC + o];
        acc0 += c * u0;
        acc1 += c * u1;
        half8 h;
        h[0]=(_Float16)u0[0]; h[1]=(_Float16)u0[1]; h[2]=(_Float16)u0[2]; h[3]=(_Float16)u0[3];
        h[4]=(_Float16)u1[0]; h[5]=(_Float16)u1[1]; h[6]=(_Float16)u1[2]; h[7]=(_Float16)u1[3];
        __builtin_nontemporal_store(h, (half8*)(obase + (size_t)r * ROW));
    }

    __shared__ float red[NWAVES * ROW];   // 8 KiB
    float* my = red + wave * ROW + elem0;
    *(f32x4*)my       = acc0;
    *(f32x4*)(my + 4) = acc1;
    __syncthreads();
    float* dst = partials + (size_t)blockIdx.x * ROW;
    for (int p = tid; p < ROW; p += 256)
        dst[p] = red[p] + red[ROW + p] + red[2*ROW + p] + red[3*ROW + p];
}

// one routing iteration: logits = b + u·w, softmax over o, s_partial = sum c*u
__global__ void __launch_bounds__(256)
pass_iter(const _Float16* __restrict__ u16, const float* __restrict__ blogit,
          const float* __restrict__ w, float* __restrict__ partials)
{
    const int tid = threadIdx.x, lane = tid & 63, wave = tid >> 6;
    const int b = blockIdx.x >> 4, chunk = blockIdx.x & 15;
    const int o = lane >> 1, elem0 = lane * 8;
    const int i_base = chunk * ROWS_PER_BLOCK + wave * 32;

    const float* wp = w + (size_t)b * ROW + elem0;
    const f32x4 w0 = *(const f32x4*)wp;
    const f32x4 w1 = *(const f32x4*)(wp + 4);

    f32x4 acc0 = {0.f,0.f,0.f,0.f}, acc1 = {0.f,0.f,0.f,0.f};

    const half8* ubase = (const half8*)(u16 + ((size_t)b * IC + i_base) * ROW + elem0);
    // row stride in half8 units: ROW/8 = 64

    half8 cur[4];
    cur[0] = ubase[0*64]; cur[1] = ubase[1*64]; cur[2] = ubase[2*64]; cur[3] = ubase[3*64];

    for (int g = 0; g < 8; ++g) {
        half8 nxt[4];
        if (g < 7) {
            const half8* p = ubase + (size_t)(g + 1) * 4 * 64;
            nxt[0] = p[0*64]; nxt[1] = p[1*64]; nxt[2] = p[2*64]; nxt[3] = p[3*64];
        }
        float blg[4];
#pragma unroll
        for (int r = 0; r < 4; ++r)
            blg[r] = blogit[(i_base + g*4 + r) * OC + o];

#pragma unroll
        for (int r = 0; r < 4; ++r) {
            float uf[8];
#pragma unroll
            for (int j = 0; j < 8; ++j) uf[j] = (float)cur[r][j];
            float part = uf[0]*w0[0] + uf[1]*w0[1] + uf[2]*w0[2] + uf[3]*w0[3]
                       + uf[4]*w1[0] + uf[5]*w1[1] + uf[6]*w1[2] + uf[7]*w1[3];
            float bb = blg[r] + part + __shfl_xor(part, 1, 64);
            // softmax over the 32 distinct o, no max-subtraction (|bb| <~ 30)
            float e = __expf(bb);
            float ssum = e;
#pragma unroll
            for (int off = 2; off <= 32; off <<= 1)
                ssum += __shfl_xor(ssum, off, 64);
            const float c = e / ssum;
            acc0[0] += c*uf[0]; acc0[1] += c*uf[1]; acc0[2] += c*uf[2]; acc0[3] += c*uf[3];
            acc1[0] += c*uf[4]; acc1[1] += c*uf[5]; acc1[2] += c*uf[6]; acc1[3] += c*uf[7];
        }
#pragma unroll
        for (int r = 0; r < 4; ++r) cur[r] = nxt[r];
    }

    __shared__ float red[NWAVES * ROW];   // 8 KiB
    float* my = red + wave * ROW + elem0;
    *(f32x4*)my       = acc0;
    *(f32x4*)(my + 4) = acc1;
    __syncthreads();
    float* dst = partials + (size_t)blockIdx.x * ROW;
    for (int p = tid; p < ROW; p += 256)
        dst[p] = red[p] + red[ROW + p] + red[2*ROW + p] + red[3*ROW + p];
}

// sum 16 partials per (b,p), squash over d, update w / write output.
// MODE 0: w = v   MODE 1: w += v   MODE 2: out = v
template<int MODE>
__global__ void __launch_bounds__(256)
reduce_squash(const float* __restrict__ partials, float* __restrict__ w,
              float* __restrict__ out)
{
    const int idx = blockIdx.x * 256 + threadIdx.x;  // over BATCH*ROW = 65536
    const int b = idx >> 9, p = idx & 511;
    const float* pp = partials + (size_t)(b * BPB) * ROW + p;
    float s = 0.f;
#pragma unroll
    for (int k = 0; k < BPB; ++k) s += pp[k * ROW];
    float sq = s * s;
    sq += __shfl_xor(sq, 1, 64);
    sq += __shfl_xor(sq, 2, 64);
    sq += __shfl_xor(sq, 4, 64);
    sq += __shfl_xor(sq, 8, 64);
    const float v = s * (sqrtf(sq) / (1.0f + sq));
    if (MODE == 0)      w[idx] = v;
    else if (MODE == 1) w[idx] += v;
    else                out[idx] = v;
}

extern "C" void kernel_launch(void* const* d_in, const int* in_sizes, int n_in,
                              void* d_out, int out_size, void* d_ws, size_t ws_size,
                              hipStream_t stream)
{
    const float* u  = (const float*)d_in[0];   // [128,2048,32,16] fp32
    const float* bl = (const float*)d_in[1];   // [2048,32] fp32
    float* out = (float*)d_out;                // [128,32,16] fp32

    char* ws = (char*)d_ws;
    _Float16* u16     = (_Float16*)(ws + OFF_U16);
    float*    partials= (float*)(ws + OFF_PART);
    float*    wbuf    = (float*)(ws + OFF_W);
    float*    c0      = (float*)(ws + OFF_C0);

    const dim3 blk(256);
    const dim3 gpass(BATCH * BPB);             // 2048
    const dim3 gred(BATCH * ROW / 256);        // 256

    softmax_b   <<<dim3(IC * OC / 256), blk, 0, stream>>>(bl, c0);
    pass0_convert<<<gpass, blk, 0, stream>>>(u, c0, u16, partials);
    reduce_squash<0><<<gred, blk, 0, stream>>>(partials, wbuf, out);
    pass_iter   <<<gpass, blk, 0, stream>>>(u16, bl, wbuf, partials);
    reduce_squash<1><<<gred, blk, 0, stream>>>(partials, wbuf, out);
    pass_iter   <<<gpass, blk, 0, stream>>>(u16, bl, wbuf, partials);
    reduce_squash<1><<<gred, blk, 0, stream>>>(partials, wbuf, out);
    pass_iter   <<<gpass, blk, 0, stream>>>(u16, bl, wbuf, partials);
    reduce_squash<2><<<gred, blk, 0, stream>>>(partials, wbuf, out);
}